// Round 6
// baseline (158.113 us; speedup 1.0000x reference)
//
#include <hip/hip_runtime.h>

#define D 64
#define KCODES 512
#define BLOCK 1024       // 16 waves
#define RPB 256          // rows/block: 16 waves x 16 rows -> grid 512 = 2 blocks/CU
#define SSTR 513         // hi-seg stride in 16B units: 512+1 pad breaks seg-bank collision
#define HI_UNITS (8 * SSTR)                    // 4104 x 16B = 65,664 B hi LDS image
#define LO_OFF   HI_UNITS                      // lo frag buffer start (16B units)
#define LO_UNITS (KCODES * 8)                  // 4096 x 16B = 65,536 B
#define CC_OFF   ((HI_UNITS + LO_UNITS) * 16)  // byte offset of cc[512] in ws

typedef short  short4_ __attribute__((ext_vector_type(4)));
typedef short  short8  __attribute__((ext_vector_type(8)));
typedef float  f32x4   __attribute__((ext_vector_type(4)));

__device__ __forceinline__ unsigned short bf16rne(float f) {
    union { float f; unsigned u; } a; a.f = f;
    unsigned r = a.u + 0x7FFFu + ((a.u >> 16) & 1u);
    return (unsigned short)(r >> 16);
}
__device__ __forceinline__ void bf16_split(float f, unsigned short& h, unsigned short& l) {
    h = bf16rne(f);
    union { unsigned u; float f; } b; b.u = (unsigned)h << 16;
    l = bf16rne(f - b.f);
}

// Prep: split codebook once, globally. Writes to ws:
//   [0, 65664)        : hi image of (-2c) bf16, EXACT LDS layout [seg][SSTR][16B]
//   [65664, 131200)   : lo residual in per-ct FRAGMENT layout: unit
//                       u = ct*128 + sg*64 + quad*16 + col  == bytes that
//                       s_cbl[(sg*4+quad)*SSTR + ct*16+col] held in r0
//   [131200, 133248)  : cc[512] fp32
// Same validated split math as r0's prologue A; only the destinations differ.
__global__ __launch_bounds__(256) void vq_prep(const float* __restrict__ cb,
                                               float* __restrict__ ws) {
    const int e  = blockIdx.x * 256 + threadIdx.x;   // 0..8191 = (code, db)
    const int k  = e >> 4;
    const int db = e & 15;
    const int seg = db >> 1, j0 = (db & 1) * 4;
    const float4 q = ((const float4*)cb)[e];
    short4_ hh, ll;
    {
        unsigned short h_, l_;
        bf16_split(-2.f * q.x, h_, l_); hh[0] = (short)h_; ll[0] = (short)l_;
        bf16_split(-2.f * q.y, h_, l_); hh[1] = (short)h_; ll[1] = (short)l_;
        bf16_split(-2.f * q.z, h_, l_); hh[2] = (short)h_; ll[2] = (short)l_;
        bf16_split(-2.f * q.w, h_, l_); hh[3] = (short)h_; ll[3] = (short)l_;
    }
    short* wss = (short*)ws;
    *(short4_*)(wss + (seg * SSTR + k) * 8 + j0) = hh;
    const int u = (k >> 4) * 128 + (seg >> 2) * 64 + (seg & 3) * 16 + (k & 15);
    *(short4_*)(wss + (LO_OFF + u) * 8 + j0) = ll;
    // cc via 16-lane shuffle tree (lane groups aligned: db == lane&15)
    float p = fmaf(q.x, q.x, 0.f);
    p = fmaf(q.y, q.y, p); p = fmaf(q.z, q.z, p); p = fmaf(q.w, q.w, p);
    p += __shfl_xor(p, 1); p += __shfl_xor(p, 2);
    p += __shfl_xor(p, 4); p += __shfl_xor(p, 8);
    if (db == 0) ((float*)((char*)ws + CC_OFF))[k] = p;
}

// Main: hi codebook in LDS (70.8 KB -> 2 blocks/CU), lo streamed from
// L1/L2-hot frag buffer, 1 row-tile per wave.
// r6: k-loop unroll 1 (r5's unroll-2 kept 2 acc chains + 2x B-frags in
// flight: ~68 unified regs > the 64 waves-halve threshold -> 1 block/CU,
// occupancy stuck at 33%). Un-unrolled state ~56 regs fits 64, so
// (1024, 8) pins the budget at 64 WITHOUT spilling (r4 spilled because
// its state needed ~68 under the same bound). TLP (8 waves/SIMD) replaces
// the lost second MFMA chain. Numerics identical to r0.
__global__ __launch_bounds__(BLOCK, 8) void vq_main(const float* __restrict__ x,
                                                    const float* __restrict__ cb,
                                                    const float* __restrict__ ws,
                                                    float* __restrict__ out) {
    __shared__ short8 s_cbh[HI_UNITS];          // 65,664 B
    __shared__ float s_cc[KCODES];              // 2 KiB
    __shared__ float s_xx[RPB];
    __shared__ int   s_bi[RPB];
    __shared__ int   s_flag[RPB];
    __shared__ int   s_nflag;

    const int t    = threadIdx.x;
    const int w    = t >> 6;        // wave 0..15
    const int lane = t & 63;
    const int quad = lane >> 4;
    const int col  = lane & 15;
    const float4* xv4  = (const float4*)x;
    const float4* cbv4 = (const float4*)cb;

    if (t == 0) s_nflag = 0;

    // Stage hi image: linear 16B copy, coalesced, conflict-free. 5 iters.
    const short8* hi_g = (const short8*)ws;
    #pragma unroll
    for (int i = 0; i < 5; ++i) {
        const int u = i * BLOCK + t;
        if (u < HI_UNITS) s_cbh[u] = hi_g[u];
    }
    if (t < KCODES) s_cc[t] = ((const float*)((const char*)ws + CC_OFF))[t];

    // x prologue: 1 row-tile of 16 rows per wave (m = col), A-frag layout
    // d = kt*32 + quad*8 + j (validated), xx via quad-shuffle tree.
    short8 xh[2], xl[2];
    {
        const size_t row = (size_t)blockIdx.x * RPB + w * 16 + col;
        float ssq = 0.f;
        #pragma unroll
        for (int kt = 0; kt < 2; ++kt) {
            const float4 p0 = xv4[row * 16 + kt * 8 + quad * 2];
            const float4 p1 = xv4[row * 16 + kt * 8 + quad * 2 + 1];
            float v[8] = {p0.x, p0.y, p0.z, p0.w, p1.x, p1.y, p1.z, p1.w};
            short8 hh, ll;
            #pragma unroll
            for (int j = 0; j < 8; ++j) {
                unsigned short h, l;
                bf16_split(v[j], h, l);
                hh[j] = (short)h; ll[j] = (short)l;
                ssq = fmaf(v[j], v[j], ssq);
            }
            xh[kt] = hh; xl[kt] = ll;
        }
        ssq += __shfl_xor(ssq, 16);
        ssq += __shfl_xor(ssq, 32);
        if (quad == 0) s_xx[w * 16 + col] = ssq;
    }

    float best[4], second[4]; int bis[4];
    #pragma unroll
    for (int i = 0; i < 4; ++i) { best[i] = __builtin_inff(); second[i] = __builtin_inff(); bis[i] = 0; }

    __syncthreads();    // hi + cc + xx ready; k-loop barrier-free

    // k-loop: 2 ds_read_b128 (hi) + 2 coalesced global dwordx4 (lo, L1/L2-hot)
    // + 6-MFMA chain per ct. acc init = cck (xx shift dropped: argmin-order
    // invariant; fallback uses s_xx for true distances). unroll 1: registers
    // over ILP — occupancy supplies the parallelism.
    const short8* lo_g = (const short8*)ws + LO_OFF;
    #pragma unroll 1
    for (int ct = 0; ct < KCODES / 16; ++ct) {
        const int k = ct * 16 + col;
        short8 ch0 = s_cbh[quad * SSTR + k];
        short8 ch1 = s_cbh[(4 + quad) * SSTR + k];
        short8 cl0 = lo_g[ct * 128 + lane];
        short8 cl1 = lo_g[ct * 128 + 64 + lane];
        const float cck = s_cc[k];
        f32x4 acc;
        #pragma unroll
        for (int r = 0; r < 4; ++r) acc[r] = cck;
        acc = __builtin_amdgcn_mfma_f32_16x16x32_bf16(xh[0], ch0, acc, 0, 0, 0);
        acc = __builtin_amdgcn_mfma_f32_16x16x32_bf16(xl[0], ch0, acc, 0, 0, 0);
        acc = __builtin_amdgcn_mfma_f32_16x16x32_bf16(xh[0], cl0, acc, 0, 0, 0);
        acc = __builtin_amdgcn_mfma_f32_16x16x32_bf16(xh[1], ch1, acc, 0, 0, 0);
        acc = __builtin_amdgcn_mfma_f32_16x16x32_bf16(xl[1], ch1, acc, 0, 0, 0);
        acc = __builtin_amdgcn_mfma_f32_16x16x32_bf16(xh[1], cl1, acc, 0, 0, 0);
        #pragma unroll
        for (int r = 0; r < 4; ++r) {
            const float dist = acc[r];
            second[r] = fminf(second[r], fmaxf(best[r], dist));
            if (dist < best[r]) { best[r] = dist; bis[r] = k; }
        }
    }

    // argmin across the 16 code-lanes per row (validated)
    #pragma unroll
    for (int r = 0; r < 4; ++r) {
        float b = best[r], s2 = second[r]; int bi = bis[r];
        #pragma unroll
        for (int off = 1; off < 16; off <<= 1) {
            float ob  = __shfl_xor(b, off);
            int   obi = __shfl_xor(bi, off);
            float os  = __shfl_xor(s2, off);
            s2 = fminf(fminf(s2, os), fmaxf(b, ob));
            if (ob < b || (ob == b && obi < bi)) { b = ob; bi = obi; }
        }
        if (col == 0) {
            const int row = w * 16 + quad * 4 + r;
            s_bi[row] = bi;
            if (s2 - b < 1e-3f) {
                int p = atomicAdd(&s_nflag, 1);
                s_flag[p] = row;
            }
        }
    }
    __syncthreads();

    // exact fp32 re-argmin, thin inverted form (validated; ~0.3% rows)
    const int nf = s_nflag;
    for (int i = w; i < nf; i += 16) {
        const int row = s_flag[i];
        const size_t gr = (size_t)blockIdx.x * RPB + row;
        const float xxv = s_xx[row];
        float dot0[8], dot1[8];
        #pragma unroll
        for (int kk = 0; kk < 8; ++kk) { dot0[kk] = 0.f; dot1[kk] = 0.f; }
        for (int db = 0; db < 16; ++db) {
            const float4 xqv = xv4[gr * 16 + db];
            #pragma unroll
            for (int kk = 0; kk < 8; ++kk) {
                const float4 cq = cbv4[(lane * 8 + kk) * 16 + db];
                dot0[kk] = fmaf(xqv.x, cq.x, dot0[kk]);
                dot1[kk] = fmaf(xqv.y, cq.y, dot1[kk]);
                dot0[kk] = fmaf(xqv.z, cq.z, dot0[kk]);
                dot1[kk] = fmaf(xqv.w, cq.w, dot1[kk]);
            }
        }
        float b = __builtin_inff(); int bi = 0;
        #pragma unroll
        for (int kk = 0; kk < 8; ++kk) {
            const int k = lane * 8 + kk;
            const float dist = (xxv - 2.f * (dot0[kk] + dot1[kk])) + s_cc[k];
            if (dist < b) { b = dist; bi = k; }
        }
        #pragma unroll
        for (int off = 1; off < 64; off <<= 1) {
            float ob  = __shfl_xor(b, off);
            int   obi = __shfl_xor(bi, off);
            if (ob < b || (ob == b && obi < bi)) { b = ob; bi = obi; }
        }
        if (lane == 0) s_bi[row] = bi;
    }
    __syncthreads();

    // coalesced gather+store (validated)
    float4* outv = (float4*)out + (size_t)blockIdx.x * (RPB * 16);
    #pragma unroll
    for (int j = 0; j < RPB * 16 / BLOCK; ++j) {
        const int f4 = j * BLOCK + t;
        const int r  = f4 >> 4;
        const int q  = f4 & 15;
        outv[f4] = cbv4[s_bi[r] * 16 + q];
    }
}

extern "C" void kernel_launch(void* const* d_in, const int* in_sizes, int n_in,
                              void* d_out, int out_size, void* d_ws, size_t ws_size,
                              hipStream_t stream) {
    const float* x  = (const float*)d_in[0];   // 131072 x 64
    const float* cb = (const float*)d_in[1];   // 512 x 64
    float* out = (float*)d_out;

    const int N = in_sizes[0] / D;             // 131072
    vq_prep<<<KCODES * 16 / 256, 256, 0, stream>>>(cb, (float*)d_ws);
    vq_main<<<N / RPB, BLOCK, 0, stream>>>(x, cb, (const float*)d_ws, out);
}

// Round 7
// 154.360 us; speedup vs baseline: 1.0243x; 1.0243x over previous
//
#include <hip/hip_runtime.h>

#define D 64
#define KCODES 512
#define BLOCK 1024       // 16 waves
#define RPB 256          // rows/block: 16 waves x 16 rows -> grid 512 = 2 blocks/CU
#define SSTR 513         // hi-seg stride in 16B units: 512+1 pad breaks seg-bank collision
#define HI_UNITS (8 * SSTR)                    // 4104 x 16B = 65,664 B hi LDS image
#define LO_OFF   HI_UNITS                      // lo frag buffer start (16B units)
#define LO_UNITS (KCODES * 8)                  // 4096 x 16B = 65,536 B
#define CC_OFF   ((HI_UNITS + LO_UNITS) * 16)  // byte offset of cc[512] in ws

typedef short  short4_ __attribute__((ext_vector_type(4)));
typedef short  short8  __attribute__((ext_vector_type(8)));
typedef float  f32x4   __attribute__((ext_vector_type(4)));

__device__ __forceinline__ unsigned short bf16rne(float f) {
    union { float f; unsigned u; } a; a.f = f;
    unsigned r = a.u + 0x7FFFu + ((a.u >> 16) & 1u);
    return (unsigned short)(r >> 16);
}
__device__ __forceinline__ void bf16_split(float f, unsigned short& h, unsigned short& l) {
    h = bf16rne(f);
    union { unsigned u; float f; } b; b.u = (unsigned)h << 16;
    l = bf16rne(f - b.f);
}

// Prep: split codebook once, globally. Writes to ws:
//   [0, 65664)        : hi image of (-2c) bf16, EXACT LDS layout [seg][SSTR][16B]
//   [65664, 131200)   : lo residual in per-ct FRAGMENT layout: unit
//                       u = ct*128 + sg*64 + quad*16 + col  == bytes that
//                       s_cbl[(sg*4+quad)*SSTR + ct*16+col] held in r0
//   [131200, 133248)  : cc[512] fp32
// Same validated split math as r0's prologue A; only the destinations differ.
__global__ __launch_bounds__(256) void vq_prep(const float* __restrict__ cb,
                                               float* __restrict__ ws) {
    const int e  = blockIdx.x * 256 + threadIdx.x;   // 0..8191 = (code, db)
    const int k  = e >> 4;
    const int db = e & 15;
    const int seg = db >> 1, j0 = (db & 1) * 4;
    const float4 q = ((const float4*)cb)[e];
    short4_ hh, ll;
    {
        unsigned short h_, l_;
        bf16_split(-2.f * q.x, h_, l_); hh[0] = (short)h_; ll[0] = (short)l_;
        bf16_split(-2.f * q.y, h_, l_); hh[1] = (short)h_; ll[1] = (short)l_;
        bf16_split(-2.f * q.z, h_, l_); hh[2] = (short)h_; ll[2] = (short)l_;
        bf16_split(-2.f * q.w, h_, l_); hh[3] = (short)h_; ll[3] = (short)l_;
    }
    short* wss = (short*)ws;
    *(short4_*)(wss + (seg * SSTR + k) * 8 + j0) = hh;
    const int u = (k >> 4) * 128 + (seg >> 2) * 64 + (seg & 3) * 16 + (k & 15);
    *(short4_*)(wss + (LO_OFF + u) * 8 + j0) = ll;
    // cc via 16-lane shuffle tree (lane groups aligned: db == lane&15)
    float p = fmaf(q.x, q.x, 0.f);
    p = fmaf(q.y, q.y, p); p = fmaf(q.z, q.z, p); p = fmaf(q.w, q.w, p);
    p += __shfl_xor(p, 1); p += __shfl_xor(p, 2);
    p += __shfl_xor(p, 4); p += __shfl_xor(p, 8);
    if (db == 0) ((float*)((char*)ws + CC_OFF))[k] = p;
}

// Main: hi codebook in LDS (70.8 KB -> 2 blocks/CU needs total regs <= 64),
// lo streamed from L1/L2-hot frag buffer, 1 row-tile per wave.
// r7 register story (3 data points):
//   r5  (1024,4) unroll-2: VGPR 60 + acc, clean, but total > 64 cliff -> 33% occ.
//   r4/r6 (1024,8): compiler panic-split 32 arch + accum -> 31 MB spills, 54% occ, 91 us
//         (clean extrapolation ~50 us -> occupancy lever is real).
// r7: unroll-1 + sequenced k-loop body (two {load group -> 3 MFMA} halves
// separated by sched_barrier(0) walls). Walls cap in-flight B-frags at 8 regs
// (not 16) and stop cross-iter hoisting -> live set ~52. Bound stays (1024,4)
// so the allocator is never forced into the 32/32 spill mode. MFMA order is
// unchanged (already grouped ch0/cl0 then ch1/cl1) -> bit-identical numerics.
__global__ __launch_bounds__(BLOCK, 4) void vq_main(const float* __restrict__ x,
                                                    const float* __restrict__ cb,
                                                    const float* __restrict__ ws,
                                                    float* __restrict__ out) {
    __shared__ short8 s_cbh[HI_UNITS];          // 65,664 B
    __shared__ float s_cc[KCODES];              // 2 KiB
    __shared__ float s_xx[RPB];
    __shared__ int   s_bi[RPB];
    __shared__ int   s_flag[RPB];
    __shared__ int   s_nflag;

    const int t    = threadIdx.x;
    const int w    = t >> 6;        // wave 0..15
    const int lane = t & 63;
    const int quad = lane >> 4;
    const int col  = lane & 15;
    const float4* xv4  = (const float4*)x;
    const float4* cbv4 = (const float4*)cb;

    if (t == 0) s_nflag = 0;

    // Stage hi image: linear 16B copy, coalesced, conflict-free. 5 iters.
    const short8* hi_g = (const short8*)ws;
    #pragma unroll
    for (int i = 0; i < 5; ++i) {
        const int u = i * BLOCK + t;
        if (u < HI_UNITS) s_cbh[u] = hi_g[u];
    }
    if (t < KCODES) s_cc[t] = ((const float*)((const char*)ws + CC_OFF))[t];

    // x prologue: 1 row-tile of 16 rows per wave (m = col), A-frag layout
    // d = kt*32 + quad*8 + j (validated), xx via quad-shuffle tree.
    short8 xh[2], xl[2];
    {
        const size_t row = (size_t)blockIdx.x * RPB + w * 16 + col;
        float ssq = 0.f;
        #pragma unroll
        for (int kt = 0; kt < 2; ++kt) {
            const float4 p0 = xv4[row * 16 + kt * 8 + quad * 2];
            const float4 p1 = xv4[row * 16 + kt * 8 + quad * 2 + 1];
            float v[8] = {p0.x, p0.y, p0.z, p0.w, p1.x, p1.y, p1.z, p1.w};
            short8 hh, ll;
            #pragma unroll
            for (int j = 0; j < 8; ++j) {
                unsigned short h, l;
                bf16_split(v[j], h, l);
                hh[j] = (short)h; ll[j] = (short)l;
                ssq = fmaf(v[j], v[j], ssq);
            }
            xh[kt] = hh; xl[kt] = ll;
        }
        ssq += __shfl_xor(ssq, 16);
        ssq += __shfl_xor(ssq, 32);
        if (quad == 0) s_xx[w * 16 + col] = ssq;
    }

    float best[4], second[4]; int bis[4];
    #pragma unroll
    for (int i = 0; i < 4; ++i) { best[i] = __builtin_inff(); second[i] = __builtin_inff(); bis[i] = 0; }

    __syncthreads();    // hi + cc + xx ready; k-loop barrier-free

    // k-loop, sequenced: {ch0,cl0 load; 3 MFMA} wall {ch1,cl1 load; 3 MFMA}
    // wall {min-track}. Walls = sched_barrier(0): pure scheduler fences that
    // cap live B-frags at 8 regs and block cross-iteration hoisting. acc
    // init = cck (xx shift dropped: argmin-order invariant; fallback uses
    // s_xx for true distances).
    const short8* lo_g = (const short8*)ws + LO_OFF;
    #pragma unroll 1
    for (int ct = 0; ct < KCODES / 16; ++ct) {
        const int k = ct * 16 + col;
        const float cck = s_cc[k];
        f32x4 acc;
        #pragma unroll
        for (int r = 0; r < 4; ++r) acc[r] = cck;
        {
            short8 ch0 = s_cbh[quad * SSTR + k];
            short8 cl0 = lo_g[ct * 128 + lane];
            acc = __builtin_amdgcn_mfma_f32_16x16x32_bf16(xh[0], ch0, acc, 0, 0, 0);
            acc = __builtin_amdgcn_mfma_f32_16x16x32_bf16(xl[0], ch0, acc, 0, 0, 0);
            acc = __builtin_amdgcn_mfma_f32_16x16x32_bf16(xh[0], cl0, acc, 0, 0, 0);
        }
        __builtin_amdgcn_sched_barrier(0);
        {
            short8 ch1 = s_cbh[(4 + quad) * SSTR + k];
            short8 cl1 = lo_g[ct * 128 + 64 + lane];
            acc = __builtin_amdgcn_mfma_f32_16x16x32_bf16(xh[1], ch1, acc, 0, 0, 0);
            acc = __builtin_amdgcn_mfma_f32_16x16x32_bf16(xl[1], ch1, acc, 0, 0, 0);
            acc = __builtin_amdgcn_mfma_f32_16x16x32_bf16(xh[1], cl1, acc, 0, 0, 0);
        }
        __builtin_amdgcn_sched_barrier(0);
        #pragma unroll
        for (int r = 0; r < 4; ++r) {
            const float dist = acc[r];
            second[r] = fminf(second[r], fmaxf(best[r], dist));
            if (dist < best[r]) { best[r] = dist; bis[r] = k; }
        }
    }

    // argmin across the 16 code-lanes per row (validated)
    #pragma unroll
    for (int r = 0; r < 4; ++r) {
        float b = best[r], s2 = second[r]; int bi = bis[r];
        #pragma unroll
        for (int off = 1; off < 16; off <<= 1) {
            float ob  = __shfl_xor(b, off);
            int   obi = __shfl_xor(bi, off);
            float os  = __shfl_xor(s2, off);
            s2 = fminf(fminf(s2, os), fmaxf(b, ob));
            if (ob < b || (ob == b && obi < bi)) { b = ob; bi = obi; }
        }
        if (col == 0) {
            const int row = w * 16 + quad * 4 + r;
            s_bi[row] = bi;
            if (s2 - b < 1e-3f) {
                int p = atomicAdd(&s_nflag, 1);
                s_flag[p] = row;
            }
        }
    }
    __syncthreads();

    // exact fp32 re-argmin, thin inverted form (validated; ~0.3% rows)
    const int nf = s_nflag;
    for (int i = w; i < nf; i += 16) {
        const int row = s_flag[i];
        const size_t gr = (size_t)blockIdx.x * RPB + row;
        const float xxv = s_xx[row];
        float dot0[8], dot1[8];
        #pragma unroll
        for (int kk = 0; kk < 8; ++kk) { dot0[kk] = 0.f; dot1[kk] = 0.f; }
        for (int db = 0; db < 16; ++db) {
            const float4 xqv = xv4[gr * 16 + db];
            #pragma unroll
            for (int kk = 0; kk < 8; ++kk) {
                const float4 cq = cbv4[(lane * 8 + kk) * 16 + db];
                dot0[kk] = fmaf(xqv.x, cq.x, dot0[kk]);
                dot1[kk] = fmaf(xqv.y, cq.y, dot1[kk]);
                dot0[kk] = fmaf(xqv.z, cq.z, dot0[kk]);
                dot1[kk] = fmaf(xqv.w, cq.w, dot1[kk]);
            }
        }
        float b = __builtin_inff(); int bi = 0;
        #pragma unroll
        for (int kk = 0; kk < 8; ++kk) {
            const int k = lane * 8 + kk;
            const float dist = (xxv - 2.f * (dot0[kk] + dot1[kk])) + s_cc[k];
            if (dist < b) { b = dist; bi = k; }
        }
        #pragma unroll
        for (int off = 1; off < 64; off <<= 1) {
            float ob  = __shfl_xor(b, off);
            int   obi = __shfl_xor(bi, off);
            if (ob < b || (ob == b && obi < bi)) { b = ob; bi = obi; }
        }
        if (lane == 0) s_bi[row] = bi;
    }
    __syncthreads();

    // coalesced gather+store (validated)
    float4* outv = (float4*)out + (size_t)blockIdx.x * (RPB * 16);
    #pragma unroll
    for (int j = 0; j < RPB * 16 / BLOCK; ++j) {
        const int f4 = j * BLOCK + t;
        const int r  = f4 >> 4;
        const int q  = f4 & 15;
        outv[f4] = cbv4[s_bi[r] * 16 + q];
    }
}

extern "C" void kernel_launch(void* const* d_in, const int* in_sizes, int n_in,
                              void* d_out, int out_size, void* d_ws, size_t ws_size,
                              hipStream_t stream) {
    const float* x  = (const float*)d_in[0];   // 131072 x 64
    const float* cb = (const float*)d_in[1];   // 512 x 64
    float* out = (float*)d_out;

    const int N = in_sizes[0] / D;             // 131072
    vq_prep<<<KCODES * 16 / 256, 256, 0, stream>>>(cb, (float*)d_ws);
    vq_main<<<N / RPB, BLOCK, 0, stream>>>(x, cb, (const float*)d_ws, out);
}

// Round 8
// 143.678 us; speedup vs baseline: 1.1005x; 1.0743x over previous
//
#include <hip/hip_runtime.h>

#define D 64
#define KCODES 512
#define BLOCK 256        // 4 waves — small blocks stagger phases across the CU
#define RPB 128          // rows/block: 4 waves x 2 tiles x 16 rows -> grid 1024
#define LOF_OFF 4096     // lo frag offset in 16B units (hi frags at 0)
#define CC_BYTE 131072   // byte offset of cc[512] in ws

typedef short  short4_ __attribute__((ext_vector_type(4)));
typedef short  short8  __attribute__((ext_vector_type(8)));
typedef float  f32x4   __attribute__((ext_vector_type(4)));

__device__ __forceinline__ unsigned short bf16rne(float f) {
    union { float f; unsigned u; } a; a.f = f;
    unsigned r = a.u + 0x7FFFu + ((a.u >> 16) & 1u);
    return (unsigned short)(r >> 16);
}
__device__ __forceinline__ void bf16_split(float f, unsigned short& h, unsigned short& l) {
    h = bf16rne(f);
    union { unsigned u; float f; } b; b.u = (unsigned)h << 16;
    l = bf16rne(f - b.f);
}

// Prep: split codebook once. Both hi and lo go to the per-ct FRAGMENT-LINEAR
// layout validated for lo in r5: unit u = ct*128 + (seg>>2)*64 + (seg&3)*16
// + (k&15), so the k-loop reads ch0/cl0 at [ct*128+lane], ch1/cl1 at +64 —
// perfectly lane-linear 1KB/wave loads, L1/L2-hot (128 KB total working set).
//   ws units [0,4096)     : hi frags (64 KB)
//   ws units [4096,8192)  : lo frags (64 KB)
//   ws bytes [131072,...) : cc[512] fp32
__global__ __launch_bounds__(256) void vq_prep(const float* __restrict__ cb,
                                               float* __restrict__ ws) {
    const int e  = blockIdx.x * 256 + threadIdx.x;   // 0..8191 = (code, db)
    const int k  = e >> 4;
    const int db = e & 15;
    const int seg = db >> 1, j0 = (db & 1) * 4;
    const float4 q = ((const float4*)cb)[e];
    short4_ hh, ll;
    {
        unsigned short h_, l_;
        bf16_split(-2.f * q.x, h_, l_); hh[0] = (short)h_; ll[0] = (short)l_;
        bf16_split(-2.f * q.y, h_, l_); hh[1] = (short)h_; ll[1] = (short)l_;
        bf16_split(-2.f * q.z, h_, l_); hh[2] = (short)h_; ll[2] = (short)l_;
        bf16_split(-2.f * q.w, h_, l_); hh[3] = (short)h_; ll[3] = (short)l_;
    }
    const int u = (k >> 4) * 128 + (seg >> 2) * 64 + (seg & 3) * 16 + (k & 15);
    short* wss = (short*)ws;
    *(short4_*)(wss + u * 8 + j0) = hh;
    *(short4_*)(wss + (LOF_OFF + u) * 8 + j0) = ll;
    // cc via 16-lane shuffle tree (lane groups aligned: db == lane&15)
    float p = fmaf(q.x, q.x, 0.f);
    p = fmaf(q.y, q.y, p); p = fmaf(q.z, q.z, p); p = fmaf(q.w, q.w, p);
    p += __shfl_xor(p, 1); p += __shfl_xor(p, 2);
    p += __shfl_xor(p, 4); p += __shfl_xor(p, 8);
    if (db == 0) ((float*)((char*)ws + CC_BYTE))[k] = p;
}

// Main, r8: NO codebook in LDS at all (~1.6 KB LDS total). 4-wave blocks,
// 4 blocks/CU, phases of different blocks interleave freely (no 16-wave
// lockstep, no staging phase). B-frags + cc stream from L1/L2-hot ws.
// 2 row-tiles/wave (r0's validated amortization halves L2 B-traffic).
// MFMA order per tile bit-identical to r0; acc init = cck (r5-validated).
__global__ __launch_bounds__(BLOCK, 4) void vq_main(const float* __restrict__ x,
                                                    const float* __restrict__ cb,
                                                    const float* __restrict__ ws,
                                                    float* __restrict__ out) {
    __shared__ float s_xx[RPB];
    __shared__ int   s_bi[RPB];
    __shared__ int   s_flag[RPB];
    __shared__ int   s_nflag;

    const int t    = threadIdx.x;
    const int w    = t >> 6;        // wave 0..3
    const int lane = t & 63;
    const int quad = lane >> 4;
    const int col  = lane & 15;
    const float4* xv4  = (const float4*)x;
    const float4* cbv4 = (const float4*)cb;

    if (t == 0) s_nflag = 0;

    // x prologue: 2 row-tiles of 16 rows per wave (m = col), A-frag layout
    // d = kt*32 + quad*8 + j (validated), xx via quad-shuffle tree.
    short8 xh[2][2], xl[2][2];
    #pragma unroll
    for (int rt = 0; rt < 2; ++rt) {
        const size_t row = (size_t)blockIdx.x * RPB + w * 32 + rt * 16 + col;
        float ssq = 0.f;
        #pragma unroll
        for (int kt = 0; kt < 2; ++kt) {
            const float4 p0 = xv4[row * 16 + kt * 8 + quad * 2];
            const float4 p1 = xv4[row * 16 + kt * 8 + quad * 2 + 1];
            float v[8] = {p0.x, p0.y, p0.z, p0.w, p1.x, p1.y, p1.z, p1.w};
            short8 hh, ll;
            #pragma unroll
            for (int j = 0; j < 8; ++j) {
                unsigned short h, l;
                bf16_split(v[j], h, l);
                hh[j] = (short)h; ll[j] = (short)l;
                ssq = fmaf(v[j], v[j], ssq);
            }
            xh[rt][kt] = hh; xl[rt][kt] = ll;
        }
        ssq += __shfl_xor(ssq, 16);
        ssq += __shfl_xor(ssq, 32);
        if (quad == 0) s_xx[w * 32 + rt * 16 + col] = ssq;
    }

    float best[8], second[8]; int bis[8];
    #pragma unroll
    for (int i = 0; i < 8; ++i) { best[i] = __builtin_inff(); second[i] = __builtin_inff(); bis[i] = 0; }

    __syncthreads();    // orders s_nflag=0 (and s_xx) before use; only barrier pre-k-loop

    // k-loop: 4 lane-linear global dwordx4 (L1/L2-hot frags) + 1 cc dword
    // + 2 independent 6-MFMA chains per ct. unroll 2: two iterations in
    // flight (~116 regs, fits the 128 cap of (256,4) with no AGPR panic).
    const short8* hif = (const short8*)ws;
    const short8* lof = hif + LOF_OFF;
    const float*  ccg = (const float*)((const char*)ws + CC_BYTE);
    #pragma unroll 2
    for (int ct = 0; ct < KCODES / 16; ++ct) {
        const int k = ct * 16 + col;
        const float cck = ccg[k];
        short8 ch0 = hif[ct * 128 + lane];
        short8 ch1 = hif[ct * 128 + 64 + lane];
        short8 cl0 = lof[ct * 128 + lane];
        short8 cl1 = lof[ct * 128 + 64 + lane];
        #pragma unroll
        for (int rt = 0; rt < 2; ++rt) {
            f32x4 acc;
            #pragma unroll
            for (int r = 0; r < 4; ++r) acc[r] = cck;
            acc = __builtin_amdgcn_mfma_f32_16x16x32_bf16(xh[rt][0], ch0, acc, 0, 0, 0);
            acc = __builtin_amdgcn_mfma_f32_16x16x32_bf16(xl[rt][0], ch0, acc, 0, 0, 0);
            acc = __builtin_amdgcn_mfma_f32_16x16x32_bf16(xh[rt][0], cl0, acc, 0, 0, 0);
            acc = __builtin_amdgcn_mfma_f32_16x16x32_bf16(xh[rt][1], ch1, acc, 0, 0, 0);
            acc = __builtin_amdgcn_mfma_f32_16x16x32_bf16(xl[rt][1], ch1, acc, 0, 0, 0);
            acc = __builtin_amdgcn_mfma_f32_16x16x32_bf16(xh[rt][1], cl1, acc, 0, 0, 0);
            #pragma unroll
            for (int r = 0; r < 4; ++r) {
                const int idx = rt * 4 + r;
                const float dist = acc[r];
                second[idx] = fminf(second[idx], fmaxf(best[idx], dist));
                if (dist < best[idx]) { best[idx] = dist; bis[idx] = k; }
            }
        }
    }

    // argmin across the 16 code-lanes per row (validated)
    #pragma unroll
    for (int rt = 0; rt < 2; ++rt) {
        #pragma unroll
        for (int r = 0; r < 4; ++r) {
            const int idx = rt * 4 + r;
            float b = best[idx], s2 = second[idx]; int bi = bis[idx];
            #pragma unroll
            for (int off = 1; off < 16; off <<= 1) {
                float ob  = __shfl_xor(b, off);
                int   obi = __shfl_xor(bi, off);
                float os  = __shfl_xor(s2, off);
                s2 = fminf(fminf(s2, os), fmaxf(b, ob));
                if (ob < b || (ob == b && obi < bi)) { b = ob; bi = obi; }
            }
            if (col == 0) {
                const int row = w * 32 + rt * 16 + quad * 4 + r;
                s_bi[row] = bi;
                if (s2 - b < 1e-3f) {
                    int p = atomicAdd(&s_nflag, 1);
                    s_flag[p] = row;
                }
            }
        }
    }
    __syncthreads();

    // exact fp32 re-argmin, thin inverted form (validated; ~0.3% rows)
    const int nf = s_nflag;
    for (int i = w; i < nf; i += 4) {
        const int row = s_flag[i];
        const size_t gr = (size_t)blockIdx.x * RPB + row;
        const float xxv = s_xx[row];
        float dot0[8], dot1[8];
        #pragma unroll
        for (int kk = 0; kk < 8; ++kk) { dot0[kk] = 0.f; dot1[kk] = 0.f; }
        for (int db = 0; db < 16; ++db) {
            const float4 xqv = xv4[gr * 16 + db];
            #pragma unroll
            for (int kk = 0; kk < 8; ++kk) {
                const float4 cq = cbv4[(lane * 8 + kk) * 16 + db];
                dot0[kk] = fmaf(xqv.x, cq.x, dot0[kk]);
                dot1[kk] = fmaf(xqv.y, cq.y, dot1[kk]);
                dot0[kk] = fmaf(xqv.z, cq.z, dot0[kk]);
                dot1[kk] = fmaf(xqv.w, cq.w, dot1[kk]);
            }
        }
        float b = __builtin_inff(); int bi = 0;
        #pragma unroll
        for (int kk = 0; kk < 8; ++kk) {
            const int k = lane * 8 + kk;
            const float dist = (xxv - 2.f * (dot0[kk] + dot1[kk])) + ccg[k];
            if (dist < b) { b = dist; bi = k; }
        }
        #pragma unroll
        for (int off = 1; off < 64; off <<= 1) {
            float ob  = __shfl_xor(b, off);
            int   obi = __shfl_xor(bi, off);
            if (ob < b || (ob == b && obi < bi)) { b = ob; bi = obi; }
        }
        if (lane == 0) s_bi[row] = bi;
    }
    __syncthreads();

    // coalesced gather+store (validated)
    float4* outv = (float4*)out + (size_t)blockIdx.x * (RPB * 16);
    #pragma unroll
    for (int j = 0; j < RPB * 16 / BLOCK; ++j) {
        const int f4 = j * BLOCK + t;
        const int r  = f4 >> 4;
        const int q  = f4 & 15;
        outv[f4] = cbv4[s_bi[r] * 16 + q];
    }
}

extern "C" void kernel_launch(void* const* d_in, const int* in_sizes, int n_in,
                              void* d_out, int out_size, void* d_ws, size_t ws_size,
                              hipStream_t stream) {
    const float* x  = (const float*)d_in[0];   // 131072 x 64
    const float* cb = (const float*)d_in[1];   // 512 x 64
    float* out = (float*)d_out;

    const int N = in_sizes[0] / D;             // 131072
    vq_prep<<<KCODES * 16 / 256, 256, 0, stream>>>(cb, (float*)d_ws);
    vq_main<<<N / RPB, BLOCK, 0, stream>>>(x, cb, (const float*)d_ws, out);
}

// Round 10
// 138.663 us; speedup vs baseline: 1.1403x; 1.0362x over previous
//
#include <hip/hip_runtime.h>

#define D 64
#define KCODES 512
#define BLOCK 256        // 4 waves = 2 k-split pairs
#define RPB 64           // rows/block: 2 pairs x 32 rows -> grid 2048 = 8 blocks/CU
#define LOF_OFF 4096     // lo frag offset in 16B units (hi frags at 0)
#define CC_BYTE 131072   // byte offset of cc[512] in ws

typedef short  short4_ __attribute__((ext_vector_type(4)));
typedef short  short8  __attribute__((ext_vector_type(8)));
typedef float  f32x4   __attribute__((ext_vector_type(4)));

__device__ __forceinline__ unsigned short bf16rne(float f) {
    union { float f; unsigned u; } a; a.f = f;
    unsigned r = a.u + 0x7FFFu + ((a.u >> 16) & 1u);
    return (unsigned short)(r >> 16);
}
__device__ __forceinline__ void bf16_split(float f, unsigned short& h, unsigned short& l) {
    h = bf16rne(f);
    union { unsigned u; float f; } b; b.u = (unsigned)h << 16;
    l = bf16rne(f - b.f);
}

// Prep (unchanged from r8, which passed): split codebook once into per-ct
// FRAGMENT-LINEAR hi/lo images + cc[512].
//   ws units [0,4096)     : hi frags (64 KB)
//   ws units [4096,8192)  : lo frags (64 KB)
//   ws bytes [131072,...) : cc[512] fp32
__global__ __launch_bounds__(256) void vq_prep(const float* __restrict__ cb,
                                               float* __restrict__ ws) {
    const int e  = blockIdx.x * 256 + threadIdx.x;   // 0..8191 = (code, db)
    const int k  = e >> 4;
    const int db = e & 15;
    const int seg = db >> 1, j0 = (db & 1) * 4;
    const float4 q = ((const float4*)cb)[e];
    short4_ hh, ll;
    {
        unsigned short h_, l_;
        bf16_split(-2.f * q.x, h_, l_); hh[0] = (short)h_; ll[0] = (short)l_;
        bf16_split(-2.f * q.y, h_, l_); hh[1] = (short)h_; ll[1] = (short)l_;
        bf16_split(-2.f * q.z, h_, l_); hh[2] = (short)h_; ll[2] = (short)l_;
        bf16_split(-2.f * q.w, h_, l_); hh[3] = (short)h_; ll[3] = (short)l_;
    }
    const int u = (k >> 4) * 128 + (seg >> 2) * 64 + (seg & 3) * 16 + (k & 15);
    short* wss = (short*)ws;
    *(short4_*)(wss + u * 8 + j0) = hh;
    *(short4_*)(wss + (LOF_OFF + u) * 8 + j0) = ll;
    float p = fmaf(q.x, q.x, 0.f);
    p = fmaf(q.y, q.y, p); p = fmaf(q.z, q.z, p); p = fmaf(q.w, q.w, p);
    p += __shfl_xor(p, 1); p += __shfl_xor(p, 2);
    p += __shfl_xor(p, 4); p += __shfl_xor(p, 8);
    if (db == 0) ((float*)((char*)ws + CC_BYTE))[k] = p;
}

// Main, r10 = r9 resubmitted (infra flake, like r3->r4). k-SPLIT to double
// resident waves: r8's counters proved the MFMA model exact (13.2% predicted
// vs 12.5% measured) and the grid = 4096 waves = 4/SIMD — the resident
// floor, so every L2 wait on the 128 KB frag buffer (L1-overflowing) is
// unhidden. Here each wave does 2 row-tiles x HALF the cts (pair member
// m = w&1 takes ct in [m*16,(m+1)*16)); 8192 waves = 8/SIMD, same per-CU
// B-traffic, per-wave k-loop VALU halved. Pair results merged in LDS with
// the SAME (best,second,idx) merge the xor-tree uses -> hedge semantics
// unchanged. MFMA order per (row-tile, ct) bit-identical to r0.
__global__ __launch_bounds__(BLOCK, 4) void vq_main(const float* __restrict__ x,
                                                    const float* __restrict__ cb,
                                                    const float* __restrict__ ws,
                                                    float* __restrict__ out) {
    __shared__ float s_xx[RPB];
    __shared__ float s_mb[2][RPB];
    __shared__ float s_ms[2][RPB];
    __shared__ int   s_mi[2][RPB];
    __shared__ int   s_bi[RPB];
    __shared__ int   s_flag[RPB];
    __shared__ int   s_nflag;

    const int t    = threadIdx.x;
    const int w    = t >> 6;        // wave 0..3
    const int lane = t & 63;
    const int quad = lane >> 4;
    const int col  = lane & 15;
    const int pr   = w >> 1;        // pair 0..1 (rows pr*32..pr*32+31)
    const int m    = w & 1;         // member: ct range [m*16, m*16+16)
    const float4* xv4  = (const float4*)x;
    const float4* cbv4 = (const float4*)cb;

    if (t == 0) s_nflag = 0;

    // x prologue: 2 row-tiles of 16 rows per wave (m = col), A-frag layout
    // d = kt*32 + quad*8 + j (validated), xx via quad-shuffle tree.
    // Both pair members compute the same rows (L1-hot reload, ~200 VALU);
    // only member 0 writes s_xx.
    short8 xh[2][2], xl[2][2];
    #pragma unroll
    for (int rt = 0; rt < 2; ++rt) {
        const size_t row = (size_t)blockIdx.x * RPB + pr * 32 + rt * 16 + col;
        float ssq = 0.f;
        #pragma unroll
        for (int kt = 0; kt < 2; ++kt) {
            const float4 p0 = xv4[row * 16 + kt * 8 + quad * 2];
            const float4 p1 = xv4[row * 16 + kt * 8 + quad * 2 + 1];
            float v[8] = {p0.x, p0.y, p0.z, p0.w, p1.x, p1.y, p1.z, p1.w};
            short8 hh, ll;
            #pragma unroll
            for (int j = 0; j < 8; ++j) {
                unsigned short h, l;
                bf16_split(v[j], h, l);
                hh[j] = (short)h; ll[j] = (short)l;
                ssq = fmaf(v[j], v[j], ssq);
            }
            xh[rt][kt] = hh; xl[rt][kt] = ll;
        }
        ssq += __shfl_xor(ssq, 16);
        ssq += __shfl_xor(ssq, 32);
        if (quad == 0 && m == 0) s_xx[pr * 32 + rt * 16 + col] = ssq;
    }

    float best[8], second[8]; int bis[8];
    #pragma unroll
    for (int i = 0; i < 8; ++i) { best[i] = __builtin_inff(); second[i] = __builtin_inff(); bis[i] = 0; }

    // k-loop over this member's 16 cts: 4 lane-linear global dwordx4
    // (L2-hot frags) + 1 cc dword + 2 independent 6-MFMA chains per ct.
    // No barrier needed before (reads only global ws).
    const short8* hif = (const short8*)ws;
    const short8* lof = hif + LOF_OFF;
    const float*  ccg = (const float*)((const char*)ws + CC_BYTE);
    #pragma unroll 2
    for (int ct = m * 16; ct < m * 16 + 16; ++ct) {
        const int k = ct * 16 + col;
        const float cck = ccg[k];
        short8 ch0 = hif[ct * 128 + lane];
        short8 ch1 = hif[ct * 128 + 64 + lane];
        short8 cl0 = lof[ct * 128 + lane];
        short8 cl1 = lof[ct * 128 + 64 + lane];
        #pragma unroll
        for (int rt = 0; rt < 2; ++rt) {
            f32x4 acc;
            #pragma unroll
            for (int r = 0; r < 4; ++r) acc[r] = cck;
            acc = __builtin_amdgcn_mfma_f32_16x16x32_bf16(xh[rt][0], ch0, acc, 0, 0, 0);
            acc = __builtin_amdgcn_mfma_f32_16x16x32_bf16(xl[rt][0], ch0, acc, 0, 0, 0);
            acc = __builtin_amdgcn_mfma_f32_16x16x32_bf16(xh[rt][0], cl0, acc, 0, 0, 0);
            acc = __builtin_amdgcn_mfma_f32_16x16x32_bf16(xh[rt][1], ch1, acc, 0, 0, 0);
            acc = __builtin_amdgcn_mfma_f32_16x16x32_bf16(xl[rt][1], ch1, acc, 0, 0, 0);
            acc = __builtin_amdgcn_mfma_f32_16x16x32_bf16(xh[rt][1], cl1, acc, 0, 0, 0);
            #pragma unroll
            for (int r = 0; r < 4; ++r) {
                const int idx = rt * 4 + r;
                const float dist = acc[r];
                second[idx] = fminf(second[idx], fmaxf(best[idx], dist));
                if (dist < best[idx]) { best[idx] = dist; bis[idx] = k; }
            }
        }
    }

    // intra-wave argmin across the 16 code-lanes per row (validated tree),
    // then publish per-member results for the pair merge.
    #pragma unroll
    for (int rt = 0; rt < 2; ++rt) {
        #pragma unroll
        for (int r = 0; r < 4; ++r) {
            const int idx = rt * 4 + r;
            float b = best[idx], s2 = second[idx]; int bi = bis[idx];
            #pragma unroll
            for (int off = 1; off < 16; off <<= 1) {
                float ob  = __shfl_xor(b, off);
                int   obi = __shfl_xor(bi, off);
                float os  = __shfl_xor(s2, off);
                s2 = fminf(fminf(s2, os), fmaxf(b, ob));
                if (ob < b || (ob == b && obi < bi)) { b = ob; bi = obi; }
            }
            if (col == 0) {
                const int row = pr * 32 + rt * 16 + quad * 4 + r;
                s_mb[m][row] = b;
                s_ms[m][row] = s2;
                s_mi[m][row] = bi;
            }
        }
    }
    __syncthreads();

    // pair merge (member 0, lanes 0-31): same merge step as the xor-tree.
    if (m == 0 && lane < 32) {
        const int row = pr * 32 + lane;
        const float ba = s_mb[0][row], bb = s_mb[1][row];
        const int   ia = s_mi[0][row], ib = s_mi[1][row];
        float b; int bi;
        if (bb < ba || (bb == ba && ib < ia)) { b = bb; bi = ib; }
        else                                 { b = ba; bi = ia; }
        const float s2 = fminf(fminf(s_ms[0][row], s_ms[1][row]), fmaxf(ba, bb));
        s_bi[row] = bi;
        if (s2 - b < 1e-3f) {
            int p = atomicAdd(&s_nflag, 1);
            s_flag[p] = row;
        }
    }
    __syncthreads();

    // exact fp32 re-argmin, thin inverted form (validated; ~0.3% rows)
    const int nf = s_nflag;
    for (int i = w; i < nf; i += 4) {
        const int row = s_flag[i];
        const size_t gr = (size_t)blockIdx.x * RPB + row;
        const float xxv = s_xx[row];
        float dot0[8], dot1[8];
        #pragma unroll
        for (int kk = 0; kk < 8; ++kk) { dot0[kk] = 0.f; dot1[kk] = 0.f; }
        for (int db = 0; db < 16; ++db) {
            const float4 xqv = xv4[gr * 16 + db];
            #pragma unroll
            for (int kk = 0; kk < 8; ++kk) {
                const float4 cq = cbv4[(lane * 8 + kk) * 16 + db];
                dot0[kk] = fmaf(xqv.x, cq.x, dot0[kk]);
                dot1[kk] = fmaf(xqv.y, cq.y, dot1[kk]);
                dot0[kk] = fmaf(xqv.z, cq.z, dot0[kk]);
                dot1[kk] = fmaf(xqv.w, cq.w, dot1[kk]);
            }
        }
        float b = __builtin_inff(); int bi = 0;
        #pragma unroll
        for (int kk = 0; kk < 8; ++kk) {
            const int k = lane * 8 + kk;
            const float dist = (xxv - 2.f * (dot0[kk] + dot1[kk])) + ccg[k];
            if (dist < b) { b = dist; bi = k; }
        }
        #pragma unroll
        for (int off = 1; off < 64; off <<= 1) {
            float ob  = __shfl_xor(b, off);
            int   obi = __shfl_xor(bi, off);
            if (ob < b || (ob == b && obi < bi)) { b = ob; bi = obi; }
        }
        if (lane == 0) s_bi[row] = bi;
    }
    __syncthreads();

    // coalesced gather+store (validated)
    float4* outv = (float4*)out + (size_t)blockIdx.x * (RPB * 16);
    #pragma unroll
    for (int j = 0; j < RPB * 16 / BLOCK; ++j) {
        const int f4 = j * BLOCK + t;
        const int r  = f4 >> 4;
        const int q  = f4 & 15;
        outv[f4] = cbv4[s_bi[r] * 16 + q];
    }
}

extern "C" void kernel_launch(void* const* d_in, const int* in_sizes, int n_in,
                              void* d_out, int out_size, void* d_ws, size_t ws_size,
                              hipStream_t stream) {
    const float* x  = (const float*)d_in[0];   // 131072 x 64
    const float* cb = (const float*)d_in[1];   // 512 x 64
    float* out = (float*)d_out;

    const int N = in_sizes[0] / D;             // 131072
    vq_prep<<<KCODES * 16 / 256, 256, 0, stream>>>(cb, (float*)d_ws);
    vq_main<<<N / RPB, BLOCK, 0, stream>>>(x, cb, (const float*)d_ws, out);
}